// Round 8
// baseline (3291.515 us; speedup 1.0000x reference)
//
#include <hip/hip_runtime.h>

#define T_STEPS 784
#define H 512
#define NBATCH 128
#define OUTC 10
#define ZROW 512   // zero-row index appended to W2T/W3T

// out layout (floats): outputs[128*10] | fr1[128*512] | fr2 | fr3 | layer_fr[3]
#define OFF_OUT   0
#define OFF_FR1   1280
#define OFF_FR2   66816
#define OFF_FR3   132352
#define OFF_LFR   197888

// raw barrier: drain LDS ops for visibility, do NOT drain vmcnt (prefetches fly)
#define BARRIER() asm volatile("s_waitcnt lgkmcnt(0)\n\ts_barrier" ::: "memory")

__global__ __launch_bounds__(256) void prep_kernel(
    const float* __restrict__ W2, const float* __restrict__ W3,
    const float* __restrict__ m1, const float* __restrict__ m2, const float* __restrict__ m3,
    float* __restrict__ W2T, float* __restrict__ W3T,
    unsigned char* __restrict__ mP, float* __restrict__ out_tail)
{
    int tid = blockIdx.x * blockDim.x + threadIdx.x;
    int stride = gridDim.x * blockDim.x;
    for (int p = tid; p < H * H; p += stride) {
        int i = p >> 9, j = p & (H - 1);
        W2T[p] = W2[j * H + i];
        W3T[p] = W3[j * H + i];
    }
    for (int p = tid; p < H; p += stride) {
        W2T[H * H + p] = 0.f;
        W3T[H * H + p] = 0.f;
    }
    for (int p = tid; p < T_STEPS * H; p += stride) {
        int t = p >> 9, i = p & (H - 1);
        unsigned char b = 0;
        if (m1[i * T_STEPS + t] != 0.f) b |= 1;
        if (m2[i * T_STEPS + t] != 0.f) b |= 2;
        if (m3[i * T_STEPS + t] != 0.f) b |= 4;
        mP[p] = b;
    }
    if (tid < 3) out_tail[tid] = 0.f;
}

__global__ __launch_bounds__(1024) void snn_kernel(
    const float* __restrict__ x,
    const float* __restrict__ W1, const float* __restrict__ b1,
    const float* __restrict__ b2, const float* __restrict__ b3,
    const float* __restrict__ W4, const float* __restrict__ b4,
    const float* __restrict__ W2T, const float* __restrict__ W3T,
    const unsigned char* __restrict__ mP,
    float* __restrict__ out)
{
    const int n = blockIdx.x;
    const int tid = threadIdx.x;
    const int lane = tid & 63;
    const int wid = tid >> 6;          // 0..15
    const int kg = tid >> 7;           // k-group 0..7 (uniform per wave-pair)
    const int g = tid & 127;           // column group: cols 4g..4g+3
    const bool upd = tid < H;          // wid<8: neuron-owner waves

    __shared__ float x_lds[T_STEPS];
    __shared__ float pacc2[8 * H];     // 16 KB k-partials, layer 2
    __shared__ float pacc3[8 * H];     // 16 KB k-partials, layer 3
    __shared__ short list1[H];         // 8 wave-local segments of 64
    __shared__ short list2[H];
    __shared__ unsigned long long cnt1w, cnt2w;  // 8 packed count bytes
    __shared__ float acc10[16];
    __shared__ float rsum[3];

    for (int t = tid; t < T_STEPS; t += 1024) x_lds[t] = x[n * T_STEPS + t];

    float mem1 = 0.f, mem2 = 0.f, mem3 = 0.f;
    float s1 = 0.f, s2 = 0.f, s3 = 0.f;
    float c1 = 0.f, c2 = 0.f, c3 = 0.f;
    float w1 = 0.f, b1v = 0.f, b2v = 0.f, b3v = 0.f;
    if (upd) { w1 = W1[tid]; b1v = b1[tid]; b2v = b2[tid]; b3v = b3[tid]; }
    const unsigned long long lt = (1ull << lane) - 1ull;
    const float4* __restrict__ Wg2 = (const float4*)W2T + g;  // row i -> Wg2[i<<7]
    const float4* __restrict__ Wg3 = (const float4*)W3T + g;

    unsigned char mb = upd ? mP[tid] : (unsigned char)0;
    unsigned int  mw = ((const unsigned int*)mP)[g];

    __syncthreads();   // x_lds ready (full barrier, outside hot loop pattern)

    // register-only segment walk over 8 wave-local lists; wave-uniform state
#define NEXT_IDX(cw, list, iv) \
    while (seg < 8 && off >= cs) { off -= cs; ++seg; \
        cs = (seg < 8) ? (int)((cw >> (8 * seg)) & 0xFFull) : 0x7fffffff; } \
    iv = (seg < 8) ? (int)list[(seg << 6) + off] : ZROW; \
    ++off;

#define GATHER(cw, list, Wg, gany, pacc, cntv) { \
    int b0 = (int)(cw & 0xFF),        bq1 = (int)((cw >> 8) & 0xFF); \
    int bq2 = (int)((cw >> 16) & 0xFF), bq3 = (int)((cw >> 24) & 0xFF); \
    int bq4 = (int)((cw >> 32) & 0xFF), bq5 = (int)((cw >> 40) & 0xFF); \
    int bq6 = (int)((cw >> 48) & 0xFF), bq7 = (int)((cw >> 56) & 0xFF); \
    cntv = ((b0 + bq1) + (bq2 + bq3)) + ((bq4 + bq5) + (bq6 + bq7)); \
    int share = ((cntv + 31) & ~31) >> 3; \
    if (gany && share > 0) { \
        int seg = 0, off = kg * share, cs = b0; \
        float4 aA = make_float4(0.f, 0.f, 0.f, 0.f); \
        float4 aB = make_float4(0.f, 0.f, 0.f, 0.f); \
        for (int p = 0; p < share; p += 4) { \
            int i0, i1, i2, i3; \
            NEXT_IDX(cw, list, i0); \
            NEXT_IDX(cw, list, i1); \
            NEXT_IDX(cw, list, i2); \
            NEXT_IDX(cw, list, i3); \
            float4 g0 = Wg[i0 << 7]; \
            float4 g1 = Wg[i1 << 7]; \
            float4 g2 = Wg[i2 << 7]; \
            float4 g3 = Wg[i3 << 7]; \
            aA.x += g0.x; aA.y += g0.y; aA.z += g0.z; aA.w += g0.w; \
            aB.x += g1.x; aB.y += g1.y; aB.z += g1.z; aB.w += g1.w; \
            aA.x += g2.x; aA.y += g2.y; aA.z += g2.z; aA.w += g2.w; \
            aB.x += g3.x; aB.y += g3.y; aB.z += g3.z; aB.w += g3.w; \
        } \
        float4 s4; \
        s4.x = aA.x + aB.x; s4.y = aA.y + aB.y; \
        s4.z = aA.z + aB.z; s4.w = aA.w + aB.w; \
        ((float4*)pacc)[(kg << 7) + g] = s4; \
    } }

    for (int t = 0; t < T_STEPS; ++t) {
        // ---- R1: layer-1 update + wave-local compact (upd); mask prefetch (all)
        if (upd) {
            float nm = mem1 * (0.2f * (1.f - s1)) + x_lds[t] * w1 + b1v;
            if (mb & 1) mem1 = nm;
            bool f1 = (mb & 1) && (mem1 > 0.5f);
            s1 = f1 ? 1.f : 0.f;  c1 += s1;
            unsigned long long ball = __ballot(f1);
            if (lane == 0)
                ((unsigned char*)&cnt1w)[wid] = (unsigned char)__popcll(ball);
            if (f1) list1[(wid << 6) + __popcll(ball & lt)] = (short)tid;
        }
        const int tn = (t + 1 < T_STEPS) ? t + 1 : t;
        unsigned char mbn = upd ? mP[tn * H + tid] : (unsigned char)0;
        unsigned int  mwn = ((const unsigned int*)(mP + tn * H))[g];
        const bool g2any = (mw & 0x02020202u) != 0u;
        const bool g3any = (mw & 0x04040404u) != 0u;
        const bool k2 = upd && ((mb & 2) != 0);
        const bool k3 = upd && ((mb & 4) != 0);

        BARRIER();   // B1: list1 + cnt1w visible

        // ---- R2: gather W2 -> pacc2 (all waves, balanced walk over segments)
        int cnt1;
        {
            unsigned long long cw = cnt1w;
            GATHER(cw, list1, Wg2, g2any, pacc2, cnt1);
        }
        BARRIER();   // C1: pacc2 visible

        // ---- R3: reduce + layer-2 update + wave-local compact (upd)
        if (upd) {
            if (k2) {
                float sx = 0.f;
                if (cnt1 > 0) {
                    float p0 = pacc2[tid]         + pacc2[H + tid];
                    float p1 = pacc2[2 * H + tid] + pacc2[3 * H + tid];
                    float p2 = pacc2[4 * H + tid] + pacc2[5 * H + tid];
                    float p3 = pacc2[6 * H + tid] + pacc2[7 * H + tid];
                    sx = (p0 + p1) + (p2 + p3);
                }
                mem2 = mem2 * (0.2f * (1.f - s2)) + sx + b2v;
            }
            bool f2 = k2 && (mem2 > 0.5f);
            s2 = f2 ? 1.f : 0.f;  c2 += s2;
            unsigned long long ball = __ballot(f2);
            if (lane == 0)
                ((unsigned char*)&cnt2w)[wid] = (unsigned char)__popcll(ball);
            if (f2) list2[(wid << 6) + __popcll(ball & lt)] = (short)tid;
        }
        BARRIER();   // B2: list2 + cnt2w visible

        // ---- R4: gather W3 -> pacc3
        int cnt2;
        {
            unsigned long long cw = cnt2w;
            GATHER(cw, list2, Wg3, g3any, pacc3, cnt2);
        }
        BARRIER();   // C2: pacc3 visible

        // ---- R5: reduce + layer-3 update (upd)
        if (upd) {
            if (k3) {
                float sx = 0.f;
                if (cnt2 > 0) {
                    float p0 = pacc3[tid]         + pacc3[H + tid];
                    float p1 = pacc3[2 * H + tid] + pacc3[3 * H + tid];
                    float p2 = pacc3[4 * H + tid] + pacc3[5 * H + tid];
                    float p3 = pacc3[6 * H + tid] + pacc3[7 * H + tid];
                    sx = (p0 + p1) + (p2 + p3);
                }
                mem3 = mem3 * (0.2f * (1.f - s3)) + sx + b3v;
            }
            bool f3 = k3 && (mem3 > 0.5f);
            s3 = f3 ? 1.f : 0.f;  c3 += s3;
        }
        mb = mbn;  mw = mwn;
    }

    __syncthreads();   // leave raw-barrier regime before epilogue

    // ---- epilogue ----
    const float inv_t = 1.f / (float)T_STEPS;
    if (upd) {
        out[OFF_FR1 + n * H + tid] = c1 * inv_t;
        out[OFF_FR2 + n * H + tid] = c2 * inv_t;
        out[OFF_FR3 + n * H + tid] = c3 * inv_t;
    }
    if (tid < 16) acc10[tid] = 0.f;
    if (tid < 3)  rsum[tid] = 0.f;
    __syncthreads();

    if (upd) {
        for (int o = 0; o < OUTC; ++o) {
            float v = c3 * W4[o * H + tid];
            for (int m = 32; m; m >>= 1) v += __shfl_xor(v, m, 64);
            if (lane == 0) atomicAdd(&acc10[o], v);
        }
        float v1 = c1, v2 = c2, v3 = c3;
        for (int m = 32; m; m >>= 1) {
            v1 += __shfl_xor(v1, m, 64);
            v2 += __shfl_xor(v2, m, 64);
            v3 += __shfl_xor(v3, m, 64);
        }
        if (lane == 0) {
            atomicAdd(&rsum[0], v1);
            atomicAdd(&rsum[1], v2);
            atomicAdd(&rsum[2], v3);
        }
    }
    __syncthreads();
    if (tid < OUTC) out[OFF_OUT + n * OUTC + tid] = acc10[tid] * inv_t + b4[tid];
    if (tid == 0) {
        const float sc = 1.f / ((float)NBATCH * (float)H * (float)T_STEPS);
        atomicAdd(&out[OFF_LFR + 0], rsum[0] * sc);
        atomicAdd(&out[OFF_LFR + 1], rsum[1] * sc);
        atomicAdd(&out[OFF_LFR + 2], rsum[2] * sc);
    }
}

extern "C" void kernel_launch(void* const* d_in, const int* in_sizes, int n_in,
                              void* d_out, int out_size, void* d_ws, size_t ws_size,
                              hipStream_t stream)
{
    const float* x  = (const float*)d_in[0];
    const float* W1 = (const float*)d_in[1];
    const float* b1 = (const float*)d_in[2];
    const float* W2 = (const float*)d_in[3];
    const float* b2 = (const float*)d_in[4];
    const float* W3 = (const float*)d_in[5];
    const float* b3 = (const float*)d_in[6];
    const float* W4 = (const float*)d_in[7];
    const float* b4 = (const float*)d_in[8];
    const float* m1 = (const float*)d_in[9];
    const float* m2 = (const float*)d_in[10];
    const float* m3 = (const float*)d_in[11];
    float* out = (float*)d_out;

    float* W2T = (float*)d_ws;                       // (H+1) x H
    float* W3T = W2T + (H + 1) * H;                  // (H+1) x H
    unsigned char* mP = (unsigned char*)(W3T + (H + 1) * H);

    hipLaunchKernelGGL(prep_kernel, dim3(512), dim3(256), 0, stream,
                       W2, W3, m1, m2, m3, W2T, W3T, mP, out + OFF_LFR);
    hipLaunchKernelGGL(snn_kernel, dim3(NBATCH), dim3(1024), 0, stream,
                       x, W1, b1, b2, b3, W4, b4, W2T, W3T, mP, out);
}

// Round 9
// 1239.431 us; speedup vs baseline: 2.6557x; 2.6557x over previous
//
#include <hip/hip_runtime.h>

#define T_STEPS 784
#define H 512
#define NBATCH 128
#define OUTC 10
#define CHUNK 32
#define NCH 25   // 24 full chunks of 32 + tail of 16

// out layout (floats): outputs[128*10] | fr1[128*512] | fr2 | fr3 | layer_fr[3]
#define OFF_OUT   0
#define OFF_FR1   1280
#define OFF_FR2   66816
#define OFF_FR3   132352
#define OFF_LFR   197888

__global__ __launch_bounds__(256) void prep_kernel(
    const float* __restrict__ W2, const float* __restrict__ W3,
    const float* __restrict__ m1, const float* __restrict__ m2, const float* __restrict__ m3,
    float* __restrict__ W2T, float* __restrict__ W3T,
    unsigned char* __restrict__ mP, float* __restrict__ out_tail)
{
    int tid = blockIdx.x * blockDim.x + threadIdx.x;
    int stride = gridDim.x * blockDim.x;
    for (int p = tid; p < H * H; p += stride) {
        int i = p >> 9, j = p & (H - 1);
        W2T[p] = W2[j * H + i];
        W3T[p] = W3[j * H + i];
    }
    for (int p = tid; p < T_STEPS * H; p += stride) {
        int t = p >> 9, i = p & (H - 1);
        unsigned char b = 0;
        if (m1[i * T_STEPS + t] != 0.f) b |= 1;
        if (m2[i * T_STEPS + t] != 0.f) b |= 2;
        if (m3[i * T_STEPS + t] != 0.f) b |= 4;
        mP[p] = b;
    }
    if (tid < 3) out_tail[tid] = 0.f;
}

// gather all set bits of one ballot word: row loads are independent -> pipeline
#define GWORD(WRD, IB, WT) { \
    unsigned long long w_ = (WRD); \
    while (w_) { \
        int b_ = __builtin_ctzll(w_); \
        w_ &= w_ - 1ull; \
        const float* rp_ = (WT) + (((IB) + b_) << 9); \
        float4 v0_ = *(const float4*)(rp_ + (lane << 2)); \
        float4 v1_ = *(const float4*)(rp_ + 256 + (lane << 2)); \
        a0.x += v0_.x; a0.y += v0_.y; a0.z += v0_.z; a0.w += v0_.w; \
        a1.x += v1_.x; a1.y += v1_.y; a1.z += v1_.z; a1.w += v1_.w; \
    } }

// one chunked layer pass: gather (all 16 waves, 2 t's each) + scan (512 thr)
#define PASS_LAYER(WT, LBIT, MEMV, SV, CV, BV, WRITE_BITS) \
  for (int ch = 0; ch < NCH; ++ch) { \
    const int tb = ch * CHUNK; \
    const int Cc = (T_STEPS - tb < CHUNK) ? (T_STEPS - tb) : CHUNK; \
    const int per = Cc >> 4; \
    __syncthreads();  /* Ibuf free; BMbuf[chunk] final */ \
    for (int q = 0; q < per; ++q) { \
      const int tl = wid * per + q; \
      const int t = tb + tl; \
      unsigned long long bw0 = BMbuf[t][0], bw1 = BMbuf[t][1]; \
      unsigned long long bw2 = BMbuf[t][2], bw3 = BMbuf[t][3]; \
      unsigned long long bw4 = BMbuf[t][4], bw5 = BMbuf[t][5]; \
      unsigned long long bw6 = BMbuf[t][6], bw7 = BMbuf[t][7]; \
      float4 a0 = make_float4(0.f, 0.f, 0.f, 0.f); \
      float4 a1 = make_float4(0.f, 0.f, 0.f, 0.f); \
      GWORD(bw0,   0, WT) GWORD(bw1,  64, WT) \
      GWORD(bw2, 128, WT) GWORD(bw3, 192, WT) \
      GWORD(bw4, 256, WT) GWORD(bw5, 320, WT) \
      GWORD(bw6, 384, WT) GWORD(bw7, 448, WT) \
      *(float4*)&Ibuf[tl][(lane << 2)] = a0; \
      *(float4*)&Ibuf[tl][256 + (lane << 2)] = a1; \
    } \
    __syncthreads();  /* Ibuf visible */ \
    if (upd) { \
      const int ngr = Cc >> 3; \
      unsigned char mcur[8]; float scur[8]; \
      _Pragma("unroll") \
      for (int q2 = 0; q2 < 8; ++q2) { \
        mcur[q2] = mP[(tb + q2) * H + j]; \
        scur[q2] = Ibuf[q2][j]; \
      } \
      for (int g = 0; g < ngr; ++g) { \
        unsigned char mnx[8]; float snx[8]; \
        const int nb = (g + 1) << 3; \
        const int pb = (nb < Cc) ? nb : (g << 3); \
        _Pragma("unroll") \
        for (int q2 = 0; q2 < 8; ++q2) { \
          mnx[q2] = mP[(tb + pb + q2) * H + j]; \
          snx[q2] = Ibuf[pb + q2][j]; \
        } \
        _Pragma("unroll") \
        for (int q2 = 0; q2 < 8; ++q2) { \
          const int t = tb + (g << 3) + q2; \
          const bool k_ = ((mcur[q2] >> (LBIT)) & 1) != 0; \
          float nm_ = MEMV * (0.2f * (1.f - SV)) + scur[q2] + BV; \
          if (k_) MEMV = nm_; \
          const bool f_ = k_ && (MEMV > 0.5f); \
          SV = f_ ? 1.f : 0.f; CV += SV; \
          if (WRITE_BITS) { \
            unsigned long long ball_ = __ballot(f_); \
            if (lane == 0) BMbuf[t][wid] = ball_; \
          } \
          mcur[q2] = mnx[q2]; scur[q2] = snx[q2]; \
        } \
      } \
    } \
  }

__global__ __launch_bounds__(1024) void snn_kernel(
    const float* __restrict__ x,
    const float* __restrict__ W1, const float* __restrict__ b1,
    const float* __restrict__ b2, const float* __restrict__ b3,
    const float* __restrict__ W4, const float* __restrict__ b4,
    const float* __restrict__ W2T, const float* __restrict__ W3T,
    const unsigned char* __restrict__ mP,
    float* __restrict__ out)
{
    const int n = blockIdx.x;
    const int tid = threadIdx.x;
    const int lane = tid & 63;
    const int wid = tid >> 6;      // 0..15
    const bool upd = tid < H;
    const int j = tid;             // neuron for upd threads

    __shared__ unsigned long long BMbuf[T_STEPS][8];  // 50 KB spike bitmask (per layer, in place)
    __shared__ float Ibuf[CHUNK][H];                  // 64 KB gathered inputs for one chunk
    __shared__ float x_lds[T_STEPS];                  // 3 KB
    __shared__ float acc10[16];
    __shared__ float rsum[3];

    for (int t = tid; t < T_STEPS; t += 1024) x_lds[t] = x[n * T_STEPS + t];

    float mem1 = 0.f, s1 = 0.f, c1 = 0.f;
    float mem2 = 0.f, s2 = 0.f, c2 = 0.f;
    float mem3 = 0.f, s3 = 0.f, c3 = 0.f;
    float w1 = 0.f, b1v = 0.f, b2v = 0.f, b3v = 0.f;
    if (upd) { w1 = W1[j]; b1v = b1[j]; b2v = b2[j]; b3v = b3[j]; }

    __syncthreads();   // x_lds ready

    // ---- Pass 1: layer-1 elementwise recurrence over all T; s1 bits -> BMbuf
    if (upd) {
        unsigned char cur[8];
        #pragma unroll
        for (int q = 0; q < 8; ++q) cur[q] = mP[q * H + j];
        for (int g = 0; g < 98; ++g) {
            const int tb8 = g << 3;
            unsigned char nxt[8];
            #pragma unroll
            for (int q = 0; q < 8; ++q) {
                int tnx = tb8 + 8 + q;
                if (tnx > T_STEPS - 1) tnx = T_STEPS - 1;
                nxt[q] = mP[tnx * H + j];
            }
            #pragma unroll
            for (int q = 0; q < 8; ++q) {
                const int t = tb8 + q;
                const bool k1 = (cur[q] & 1) != 0;
                float nm = mem1 * (0.2f * (1.f - s1)) + x_lds[t] * w1 + b1v;
                if (k1) mem1 = nm;
                const bool f1 = k1 && (mem1 > 0.5f);
                s1 = f1 ? 1.f : 0.f;  c1 += s1;
                unsigned long long ball = __ballot(f1);
                if (lane == 0) BMbuf[t][wid] = ball;
                cur[q] = nxt[q];
            }
        }
    }
    // (chunk-top barrier of the first pass makes BMbuf visible)

    // ---- Pass 2: layer 2 (gathers read s1 bits; scan overwrites with s2 bits)
    PASS_LAYER(W2T, 1, mem2, s2, c2, b2v, 1)

    // ---- Pass 3: layer 3 (gathers read s2 bits; no bit writes needed)
    PASS_LAYER(W3T, 2, mem3, s3, c3, b3v, 0)

    __syncthreads();

    // ---- epilogue ----
    const float inv_t = 1.f / (float)T_STEPS;
    if (upd) {
        out[OFF_FR1 + n * H + j] = c1 * inv_t;
        out[OFF_FR2 + n * H + j] = c2 * inv_t;
        out[OFF_FR3 + n * H + j] = c3 * inv_t;
    }
    if (tid < 16) acc10[tid] = 0.f;
    if (tid < 3)  rsum[tid] = 0.f;
    __syncthreads();

    if (upd) {
        for (int o = 0; o < OUTC; ++o) {
            float v = c3 * W4[o * H + j];
            for (int m = 32; m; m >>= 1) v += __shfl_xor(v, m, 64);
            if (lane == 0) atomicAdd(&acc10[o], v);
        }
        float v1 = c1, v2 = c2, v3 = c3;
        for (int m = 32; m; m >>= 1) {
            v1 += __shfl_xor(v1, m, 64);
            v2 += __shfl_xor(v2, m, 64);
            v3 += __shfl_xor(v3, m, 64);
        }
        if (lane == 0) {
            atomicAdd(&rsum[0], v1);
            atomicAdd(&rsum[1], v2);
            atomicAdd(&rsum[2], v3);
        }
    }
    __syncthreads();
    if (tid < OUTC) out[OFF_OUT + n * OUTC + tid] = acc10[tid] * inv_t + b4[tid];
    if (tid == 0) {
        const float sc = 1.f / ((float)NBATCH * (float)H * (float)T_STEPS);
        atomicAdd(&out[OFF_LFR + 0], rsum[0] * sc);
        atomicAdd(&out[OFF_LFR + 1], rsum[1] * sc);
        atomicAdd(&out[OFF_LFR + 2], rsum[2] * sc);
    }
}

extern "C" void kernel_launch(void* const* d_in, const int* in_sizes, int n_in,
                              void* d_out, int out_size, void* d_ws, size_t ws_size,
                              hipStream_t stream)
{
    const float* x  = (const float*)d_in[0];
    const float* W1 = (const float*)d_in[1];
    const float* b1 = (const float*)d_in[2];
    const float* W2 = (const float*)d_in[3];
    const float* b2 = (const float*)d_in[4];
    const float* W3 = (const float*)d_in[5];
    const float* b3 = (const float*)d_in[6];
    const float* W4 = (const float*)d_in[7];
    const float* b4 = (const float*)d_in[8];
    const float* m1 = (const float*)d_in[9];
    const float* m2 = (const float*)d_in[10];
    const float* m3 = (const float*)d_in[11];
    float* out = (float*)d_out;

    float* W2T = (float*)d_ws;                 // H x H
    float* W3T = W2T + H * H;                  // H x H
    unsigned char* mP = (unsigned char*)(W3T + H * H);

    hipLaunchKernelGGL(prep_kernel, dim3(512), dim3(256), 0, stream,
                       W2, W3, m1, m2, m3, W2T, W3T, mP, out + OFF_LFR);
    hipLaunchKernelGGL(snn_kernel, dim3(NBATCH), dim3(1024), 0, stream,
                       x, W1, b1, b2, b3, W4, b4, W2T, W3T, mP, out);
}